// Round 4
// baseline (9565.781 us; speedup 1.0000x reference)
//
#include <hip/hip_runtime.h>

typedef unsigned short ushort_t;
typedef __bf16 bf16x8 __attribute__((ext_vector_type(8)));
typedef float f32x4 __attribute__((ext_vector_type(4)));

#define T_STEPS 512
#define BATCH 64
#define HDIM 1024
#define CHUNK 32                 // steps per chunk
#define NCHUNK (T_STEPS / CHUNK) // 16
#define MCH (CHUNK * BATCH)      // 2048 rows per chunk GEMM
#define NWG 64                   // persistent workgroups (1 per CU, 64 << 256 CUs)
#define FLAG_PAD 16              // ints; 64B spacing between WG flags
#define OUTS_ELEMS 33554432ULL   // fp32 outs, then h_T [65536], c_T [65536]

#define MFMA16 __builtin_amdgcn_mfma_f32_16x16x32_bf16

__device__ __forceinline__ ushort_t f2bf(float f) {
    union { unsigned int i; float f; } v;
    v.f = f;
    unsigned int x = v.i;
    return (ushort_t)((x + 0x7FFFu + ((x >> 16) & 1u)) >> 16);
}

__device__ __forceinline__ float bf2f(ushort_t u) {
    union { unsigned int i; float f; } v;
    v.i = ((unsigned int)u) << 16;
    return v.f;
}

struct Ptr8 { const float* p[8]; };
struct Ptr4 { const float* p[4]; };

// ---------------------------------------------------------------------------
// Transpose+convert 8 fp32 weight matrices [1024 k][1024 n] -> bf16 [1024 n][1024 k]
// ---------------------------------------------------------------------------
__global__ __launch_bounds__(256) void transpose8(Ptr8 in, ushort_t* __restrict__ out) {
    __shared__ ushort_t tile[64][65];
    int z = blockIdx.z;
    const float* src = in.p[z];
    ushort_t* dst = out + (size_t)z * 1024 * 1024;
    int bx = blockIdx.x * 64;  // n base
    int by = blockIdx.y * 64;  // k base
    int t = threadIdx.x;
#pragma unroll
    for (int i = 0; i < 16; i++) {
        int lin = t + i * 256;
        int r = lin >> 6, c = lin & 63;
        tile[r][c] = f2bf(src[(size_t)(by + r) * 1024 + bx + c]);
    }
    __syncthreads();
#pragma unroll
    for (int i = 0; i < 16; i++) {
        int lin = t + i * 256;
        int r = lin >> 6, c = lin & 63;
        dst[(size_t)(bx + r) * 1024 + by + c] = tile[c][r];
    }
}

// ---------------------------------------------------------------------------
// Chunk GEMM: G[m][n'] = A[m][:] @ wt_x[n'][:] + bias (fp32 acc, bf16 out)
// A: fp32 [2048 m][1024 k]; wt_x: bf16 [4096 n'][1024 k], n' = g*1024+n
// ---------------------------------------------------------------------------
#define BK 32
#define LDK 40

__global__ __launch_bounds__(256) void chunk_gemm(
    const float* __restrict__ A,
    const ushort_t* __restrict__ Wt,
    Ptr4 biases,
    ushort_t* __restrict__ G)
{
    __shared__ ushort_t As[128 * LDK];
    __shared__ ushort_t Bs[128 * LDK];

    int n0 = blockIdx.x * 128;
    int m0 = blockIdx.y * 128;
    int t = threadIdx.x;
    int wave = t >> 6, lane = t & 63;
    int wm = (wave & 1) * 64, wn = (wave >> 1) * 64;
    int lrow = lane & 15, quad = lane >> 4;
    int lk = quad * 8;

    f32x4 acc[4][4] = {};

    for (int k0 = 0; k0 < 1024; k0 += BK) {
        __syncthreads();
#pragma unroll
        for (int i = 0; i < 4; i++) {
            int c = t + 256 * i;
            int r = c >> 3, kc = c & 7;
            const float4 v = *(const float4*)&A[(size_t)(m0 + r) * 1024 + k0 + kc * 4];
            ushort_t* d = &As[r * LDK + kc * 4];
            d[0] = f2bf(v.x); d[1] = f2bf(v.y); d[2] = f2bf(v.z); d[3] = f2bf(v.w);
        }
#pragma unroll
        for (int i = 0; i < 2; i++) {
            int c = t + 256 * i;
            int r = c >> 2, kc = c & 3;
            *(bf16x8*)&Bs[r * LDK + kc * 8] =
                *(const bf16x8*)&Wt[(size_t)(n0 + r) * 1024 + k0 + kc * 8];
        }
        __syncthreads();

        bf16x8 a[4], b[4];
#pragma unroll
        for (int i = 0; i < 4; i++)
            a[i] = *(const bf16x8*)&As[(wm + i * 16 + lrow) * LDK + lk];
#pragma unroll
        for (int j = 0; j < 4; j++)
            b[j] = *(const bf16x8*)&Bs[(wn + j * 16 + lrow) * LDK + lk];
#pragma unroll
        for (int i = 0; i < 4; i++)
#pragma unroll
            for (int j = 0; j < 4; j++)
                acc[i][j] = MFMA16(a[i], b[j], acc[i][j], 0, 0, 0);
    }

    int g = n0 >> 10;
    const float* bias = biases.p[g];
    int cg0 = (n0 & 1023) + wn;
#pragma unroll
    for (int j = 0; j < 4; j++) {
        int coln = n0 + wn + j * 16 + lrow;
        float bv = bias[cg0 + j * 16 + lrow];
#pragma unroll
        for (int i = 0; i < 4; i++) {
#pragma unroll
            for (int r = 0; r < 4; r++) {
                int rowm = m0 + wm + i * 16 + quad * 4 + r;
                G[(size_t)rowm * 4096 + coln] = f2bf(acc[i][j][r] + bv);
            }
        }
    }
}

// ---------------------------------------------------------------------------
// Init: fp32 h0/c0 -> fp32 masters + bf16 h; zero barrier flags
// ---------------------------------------------------------------------------
__global__ __launch_bounds__(256) void init_state(
    const float* __restrict__ h0, const float* __restrict__ c0,
    float* __restrict__ hf, float* __restrict__ cf, ushort_t* __restrict__ hb,
    int* __restrict__ flags)
{
    int i = blockIdx.x * 256 + threadIdx.x;  // 65536
    float h = h0[i];
    hf[i] = h;
    cf[i] = c0[i];
    hb[i] = f2bf(h);
    if (i < NWG * FLAG_PAD) flags[i] = 0;
}

// ---------------------------------------------------------------------------
// Persistent chunk recurrence: 64 WGs x 256 thr, 32 steps per launch with a
// hand-rolled device-scope barrier per step. WG wg owns hidden units
// [wg*16, wg*16+16) -> 64 virtual cols (4 gates x 16 units). Weights for the
// slice live in registers (wreg: 256 VGPRs). c / fp32-h / retention live in
// thread registers across the chunk.
// Wave tiling: wm=(w&1)*32 (batch), wn=(w>>1)*32 (vc); 2x2 MFMA tiles/wave.
// ---------------------------------------------------------------------------
__global__ __launch_bounds__(256, 1) void lstm_persist(
    const ushort_t* __restrict__ WtH,   // bf16 [4][1024 n][1024 k]
    const ushort_t* __restrict__ Gc,    // bf16 chunk gates [2048 m][4096 n']
    const float* __restrict__ ret,
    float* __restrict__ cf, float* __restrict__ hf,   // fp32 state spill
    ushort_t* __restrict__ hb0, ushort_t* __restrict__ hb1,
    int* flags,
    float* __restrict__ out,
    int chunk)
{
    __shared__ float S[64 * 65];

    int wg = blockIdx.x;
    int u0 = wg * 16;
    int tid = threadIdx.x, wave = tid >> 6, lane = tid & 63;
    int wm = (wave & 1) * 32;
    int wn = (wave >> 1) * 32;
    int lrow = lane & 15, quad = lane >> 4;

    // --- weights -> registers (read once per chunk) ---
    bf16x8 wreg[2][32];
#pragma unroll
    for (int j = 0; j < 2; j++) {
        int vc = wn + j * 16 + lrow;            // 0..63
        const ushort_t* wrow = WtH + (size_t)(vc >> 4) * 1048576
                                   + (size_t)(u0 + (vc & 15)) * 1024 + quad * 8;
#pragma unroll
        for (int kk = 0; kk < 32; kk++)
            wreg[j][kk] = *(const bf16x8*)(wrow + kk * 32);
    }

    // --- per-thread recurrent state ---
    float c[4], hm[4], rr[4];
#pragma unroll
    for (int s = 0; s < 4; s++) {
        int b = s * 16 + (tid >> 4), u = tid & 15;
        int idx = b * 1024 + u0 + u;
        c[s] = cf[idx]; hm[s] = hf[idx]; rr[s] = ret[u0 + u];
    }

    for (int tc = 0; tc < CHUNK; tc++) {
        int gstep = chunk * CHUNK + tc;
        const ushort_t* hin = (gstep & 1) ? hb1 : hb0;
        ushort_t* hout      = (gstep & 1) ? hb0 : hb1;

        // --- MFMA: S[b][vc] = h_prev @ W_slice ---
        f32x4 acc00 = {}, acc01 = {}, acc10 = {}, acc11 = {};
        const ushort_t* a0p = hin + (size_t)(wm + lrow) * 1024 + quad * 8;
        const ushort_t* a1p = a0p + 16 * 1024;
#pragma unroll
        for (int kk = 0; kk < 32; kk++) {
            bf16x8 a0 = *(const bf16x8*)(a0p + kk * 32);
            bf16x8 a1 = *(const bf16x8*)(a1p + kk * 32);
            acc00 = MFMA16(a0, wreg[0][kk], acc00, 0, 0, 0);
            acc01 = MFMA16(a0, wreg[1][kk], acc01, 0, 0, 0);
            acc10 = MFMA16(a1, wreg[0][kk], acc10, 0, 0, 0);
            acc11 = MFMA16(a1, wreg[1][kk], acc11, 0, 0, 0);
        }
#pragma unroll
        for (int r = 0; r < 4; r++) {
            S[(wm + quad * 4 + r) * 65 + wn + lrow]           = acc00[r];
            S[(wm + quad * 4 + r) * 65 + wn + 16 + lrow]      = acc01[r];
            S[(wm + 16 + quad * 4 + r) * 65 + wn + lrow]      = acc10[r];
            S[(wm + 16 + quad * 4 + r) * 65 + wn + 16 + lrow] = acc11[r];
        }
        __syncthreads();

        // --- elementwise: 4 (b,u) items per thread ---
#pragma unroll
        for (int s = 0; s < 4; s++) {
            int b = s * 16 + (tid >> 4), u = tid & 15;
            int hu = u0 + u;
            size_t gbase = ((size_t)tc * 64 + b) * 4096 + hu;
            float si = S[b * 65 + u]       + bf2f(Gc[gbase]);
            float sf = S[b * 65 + 16 + u]  + bf2f(Gc[gbase + 1024]);
            float so = S[b * 65 + 32 + u]  + bf2f(Gc[gbase + 2048]);
            float sg = S[b * 65 + 48 + u]  + bf2f(Gc[gbase + 3072]);
            float it = 1.f / (1.f + __expf(-si));
            float ft = 1.f / (1.f + __expf(-sf));
            float ot = 1.f / (1.f + __expf(-so));
            float gt = 1.f - 2.f / (__expf(2.f * sg) + 1.f);
            float cn = c[s] * ft + it * gt;
            float tcn = 1.f - 2.f / (__expf(2.f * cn) + 1.f);
            float hl = ot * tcn;
            float hn = rr[s] * hm[s] + (1.f - rr[s]) * hl;
            c[s] = cn; hm[s] = hn;
            int idx = b * 1024 + hu;
            hout[idx] = f2bf(hn);
            out[(size_t)gstep * 65536 + idx] = hn;
        }
        __syncthreads();   // all waves done: S reads finished, h stores drained (vmcnt0)

        // --- device-scope barrier (skip after last step: kernel end syncs) ---
        if (tc < CHUNK - 1) {
            int target = gstep + 1;
            if (tid == 0)
                __hip_atomic_store(&flags[wg * FLAG_PAD], target,
                                   __ATOMIC_RELEASE, __HIP_MEMORY_SCOPE_AGENT);
            if (wave == 0) {
                for (;;) {
                    int v = __hip_atomic_load(&flags[lane * FLAG_PAD],
                                              __ATOMIC_RELAXED, __HIP_MEMORY_SCOPE_AGENT);
                    if (__all(v >= target)) break;
                    __builtin_amdgcn_s_sleep(1);
                }
            }
            __syncthreads();
            __builtin_amdgcn_fence(__ATOMIC_ACQUIRE, "agent");
        }
    }

    // --- spill recurrent state for next chunk / epilogue ---
#pragma unroll
    for (int s = 0; s < 4; s++) {
        int b = s * 16 + (tid >> 4), u = tid & 15;
        int idx = b * 1024 + u0 + u;
        cf[idx] = c[s]; hf[idx] = hm[s];
    }
}

// ---------------------------------------------------------------------------
__global__ __launch_bounds__(256) void epilogue_k(
    const float* __restrict__ hf_final, const float* __restrict__ cf,
    float* __restrict__ out)
{
    int i = blockIdx.x * 256 + threadIdx.x;  // 65536
    out[OUTS_ELEMS + i] = hf_final[i];
    out[OUTS_ELEMS + 65536 + i] = cf[i];
}

// ---------------------------------------------------------------------------
extern "C" void kernel_launch(void* const* d_in, const int* in_sizes, int n_in,
                              void* d_out, int out_size, void* d_ws, size_t ws_size,
                              hipStream_t stream)
{
    const float* input_ = (const float*)d_in[0];
    const float* h0   = (const float*)d_in[1];
    const float* c0   = (const float*)d_in[2];
    const float* w_xi = (const float*)d_in[3];
    const float* w_xf = (const float*)d_in[4];
    const float* w_xo = (const float*)d_in[5];
    const float* w_xc = (const float*)d_in[6];
    const float* w_hi = (const float*)d_in[7];
    const float* w_hf = (const float*)d_in[8];
    const float* w_ho = (const float*)d_in[9];
    const float* w_hc = (const float*)d_in[10];
    const float* b_i  = (const float*)d_in[11];
    const float* b_f  = (const float*)d_in[12];
    const float* b_o  = (const float*)d_in[13];
    const float* b_c  = (const float*)d_in[14];
    const float* ret  = (const float*)d_in[15];

    // workspace carve (~32.8 MiB, same footprint class as round 3)
    ushort_t* wt_x   = (ushort_t*)d_ws;            // 8 MiB
    ushort_t* wt_h   = wt_x + 4ULL * 1048576;      // 8 MiB
    ushort_t* gchunk = wt_h + 4ULL * 1048576;      // 16 MiB
    float*  cf  = (float*)(gchunk + (size_t)MCH * 4096);
    float*  hf  = cf + 65536;
    ushort_t* hb0 = (ushort_t*)(hf + 65536);
    ushort_t* hb1 = hb0 + 65536;
    int* flags = (int*)(hb1 + 65536);
    float* out = (float*)d_out;

    Ptr8 p8; p8.p[0] = w_xi; p8.p[1] = w_xf; p8.p[2] = w_xo; p8.p[3] = w_xc;
             p8.p[4] = w_hi; p8.p[5] = w_hf; p8.p[6] = w_ho; p8.p[7] = w_hc;
    transpose8<<<dim3(16, 16, 8), 256, 0, stream>>>(p8, wt_x);

    init_state<<<256, 256, 0, stream>>>(h0, c0, hf, cf, hb0, flags);

    Ptr4 b4; b4.p[0] = b_i; b4.p[1] = b_f; b4.p[2] = b_o; b4.p[3] = b_c;

    for (int chunk = 0; chunk < NCHUNK; chunk++) {
        chunk_gemm<<<dim3(32, 16), 256, 0, stream>>>(
            input_ + (size_t)chunk * MCH * 1024, wt_x, b4, gchunk);
        lstm_persist<<<NWG, 256, 0, stream>>>(wt_h, gchunk, ret, cf, hf,
                                              hb0, hb1, flags, out, chunk);
    }

    epilogue_k<<<256, 256, 0, stream>>>(hf, cf, out);
}